// Round 11
// baseline (210.259 us; speedup 1.0000x reference)
//
#include <hip/hip_runtime.h>
#include <math.h>

#define D 256
#define NROW 16384
#define KCODE 8192
#define MARGIN 1.2e-3f   // pure-fp16 product: 2*2^-11 = 9.77e-4 worst + accum slack

typedef _Float16 half8 __attribute__((ext_vector_type(8)));
typedef _Float16 half4f __attribute__((ext_vector_type(4)));
typedef __attribute__((ext_vector_type(4))) float f32x4;

__device__ __forceinline__ float dot4(float4 a, float4 b) {
  return a.x * b.x + a.y * b.y + a.z * b.z + a.w * b.w;
}
__device__ __forceinline__ float wave_sum(float s) {
#pragma unroll
  for (int off = 32; off; off >>= 1) s += __shfl_xor(s, off, 64);
  return s;
}
__device__ __forceinline__ float wave_min_f(float v) {
#pragma unroll
  for (int off = 32; off; off >>= 1) v = fminf(v, __shfl_xor(v, off, 64));
  return v;
}
__device__ __forceinline__ void async16(const void* g, void* l) {
  __builtin_amdgcn_global_load_lds(
      (const __attribute__((address_space(1))) unsigned int*)g,
      (__attribute__((address_space(3))) unsigned int*)l, 16, 0, 0);
}

// ---------- combined prep: blocks [0,2048) emb; [2048,6144) z ----------
// fp16 copies PRE-SWIZZLED in 16x16x32-MFMA fragment order (v10 layout):
//   off = t*32768 + ph*4096 + grp*2048 + f*512 + (quad*16 + col)*8 + k&7
// where row = grp*64 + f*16 + col, ph = k>>5, quad = (k>>3)&3.
// A wave's fragment (grp,f,ph): lane l reads contiguous l*8 f16 -> 1 KB run.
__global__ __launch_bounds__(256) void k_prep(const float* __restrict__ emb,
                                              const float* __restrict__ z,
                                              float* __restrict__ emb_n,
                                              float* __restrict__ e2,
                                              _Float16* __restrict__ Bb,
                                              _Float16* __restrict__ Ab) {
  const int b = blockIdx.x;
  const int w = threadIdx.x >> 6, l = threadIdx.x & 63;
  // lane l covers k = 4l..4l+3
  const int ph = l >> 3;             // k>>5
  const int qd = (l & 7) >> 1;       // (k>>3)&3
  const int hf = l & 1;              // (k&7)>>2
  if (b < 2048) {
    int row = b * 4 + w;
    float4 v = ((const float4*)(emb + (size_t)row * D))[l];
    float s = wave_sum(dot4(v, v));
    float inv = 1.0f / sqrtf(s + 1e-12f);
    v.x *= inv; v.y *= inv; v.z *= inv; v.w *= inv;
    ((float4*)(emb_n + (size_t)row * D))[l] = v;
    float s2 = wave_sum(dot4(v, v));
    if (l == 0) e2[row] = s2;
    half4f h;
    h[0] = (_Float16)v.x; h[1] = (_Float16)v.y;
    h[2] = (_Float16)v.z; h[3] = (_Float16)v.w;
    int t = row >> 7, r = row & 127;
    size_t off = (size_t)t * 32768 + ph * 4096 + (r >> 6) * 2048 +
                 ((r >> 4) & 3) * 512 + (qd * 16 + (r & 15)) * 8 + hf * 4;
    *(half4f*)(Bb + off) = h;
  } else {
    int row = (b - 2048) * 4 + w;
    float4 v = ((const float4*)(z + (size_t)row * D))[l];
    float s = wave_sum(dot4(v, v));
    float inv = 1.0f / sqrtf(s + 1e-12f);
    v.x *= inv; v.y *= inv; v.z *= inv; v.w *= inv;
    half4f h;
    h[0] = (_Float16)v.x; h[1] = (_Float16)v.y;
    h[2] = (_Float16)v.z; h[3] = (_Float16)v.w;
    int t = row >> 7, r = row & 127;
    size_t off = (size_t)t * 32768 + ph * 4096 + (r >> 6) * 2048 +
                 ((r >> 4) & 3) * 512 + (qd * 16 + (r & 15)) * 8 + hf * 4;
    *(half4f*)(Ab + off) = h;
  }
}

__device__ __forceinline__ void merge2(float& d1, int& k1, float& d2, int& k2,
                                       float od1, int ok1, float od2, int ok2) {
  bool w1 = (od1 < d1) || (od1 == d1 && ok1 < k1);
  float n1 = w1 ? od1 : d1; int nk1 = w1 ? ok1 : k1;
  float c  = w1 ? d1 : od1; int ck  = w1 ? k1 : ok1;
  float c2 = w1 ? od2 : d2; int ck2 = w1 ? ok2 : k2;
  bool w2 = (c2 < c) || (c2 == c && ck2 < ck);
  d1 = n1; k1 = nk1;
  d2 = w2 ? c2 : c; k2 = w2 ? ck2 : ck;
}

// ---------- 128x128 fp16 GEMM (codes x z), K'=256, fused top-2 ----------
// v16: hybrid L1-relief. The zero-LDS family (v10/13/14/15 = 92-107us) is
// L1-BW-bound: 256 KB/block through L1 (each operand-half read by 2 waves)
// = 2.1 GB -> 53us floor. Fix: stage the A (code) tile in LDS ONCE per block
// (64 KB linear copy via global_load_lds, ONE barrier total - no per-step
// drain), A then feeds from the separate LDS pipe; B keeps the v10 streamed
// ping-pong (window ~620 cyc >> 200 cyc L2). L1/block 256->192 KB.
// LDS 64 KB -> 2 blocks/CU; regs ~115 (32 B-ops + 64 acc) -> no spill.
__global__ __launch_bounds__(256, 2) void k_gemm_argmin16(
    const _Float16* __restrict__ Cb,   // codes fp16, fragment-major
    const _Float16* __restrict__ Zb,   // z fp16, fragment-major
    const float* __restrict__ e2, float4* __restrict__ top2) {
  __shared__ _Float16 As[32768];       // 64 KB code tile (fragment-major)
  const int tid = threadIdx.x, w = tid >> 6, l = tid & 63;
  const int wm = w >> 1, wn = w & 1;
  const int quad = l >> 4, col = l & 15;
  const int xcd = blockIdx.x & 7;
  const int j = blockIdx.x >> 3;
  const int ct = xcd * 8 + (j & 7);          // code tile 0..63
  const int zt = j >> 3;                     // z tile 0..127
  const int c0 = ct * 128;

  const _Float16* Bt = Zb + (size_t)zt * 32768 + wn * 2048 + (size_t)l * 8;

  f32x4 acc[4][4] = {};
  half8 bU0, bU1, bU2, bU3, bV0, bV1, bV2, bV3;

  // ---- stage A tile into LDS (linear fragment-major copy, 16 chunks/thread)
  {
    const _Float16* gA = Cb + (size_t)ct * 32768;
#pragma unroll
    for (int k = 0; k < 16; ++k)
      async16(gA + (size_t)(k * 256 + tid) * 8, (char*)As + (size_t)(k * 256 + tid) * 16);
  }
  __builtin_amdgcn_sched_barrier(0);
  // B(0) prefetch issued after the 16 stages
  bU0 = *(const half8*)(Bt + 0 * 512);
  bU1 = *(const half8*)(Bt + 1 * 512);
  bU2 = *(const half8*)(Bt + 2 * 512);
  bU3 = *(const half8*)(Bt + 3 * 512);
  __builtin_amdgcn_sched_barrier(0);
  asm volatile("s_waitcnt vmcnt(4)" ::: "memory");   // 16 A-stages done; B in flight
  __builtin_amdgcn_s_barrier();
  __builtin_amdgcn_sched_barrier(0);

  // A fragment (ph, mf) at LDS halfs offset: ph*4096 + wm*2048 + mf*512 + l*8
#define KPH16(CB0, CB1, CB2, CB3, NB0, NB1, NB2, NB3, PH)                     \
  {                                                                           \
    if ((PH) < 7) {                                                           \
      NB0 = *(const half8*)(Bt + ((PH) + 1) * 4096 + 0 * 512);                \
      NB1 = *(const half8*)(Bt + ((PH) + 1) * 4096 + 1 * 512);                \
      NB2 = *(const half8*)(Bt + ((PH) + 1) * 4096 + 2 * 512);                \
      NB3 = *(const half8*)(Bt + ((PH) + 1) * 4096 + 3 * 512);                \
    }                                                                         \
    half8 af0 = *(const half8*)(As + (PH) * 4096 + wm * 2048 + 0 * 512 + l * 8); \
    half8 af1 = *(const half8*)(As + (PH) * 4096 + wm * 2048 + 1 * 512 + l * 8); \
    half8 af2 = *(const half8*)(As + (PH) * 4096 + wm * 2048 + 2 * 512 + l * 8); \
    half8 af3 = *(const half8*)(As + (PH) * 4096 + wm * 2048 + 3 * 512 + l * 8); \
    __builtin_amdgcn_s_setprio(1);                                            \
    acc[0][0] = __builtin_amdgcn_mfma_f32_16x16x32_f16(af0, CB0, acc[0][0], 0, 0, 0); \
    acc[0][1] = __builtin_amdgcn_mfma_f32_16x16x32_f16(af0, CB1, acc[0][1], 0, 0, 0); \
    acc[0][2] = __builtin_amdgcn_mfma_f32_16x16x32_f16(af0, CB2, acc[0][2], 0, 0, 0); \
    acc[0][3] = __builtin_amdgcn_mfma_f32_16x16x32_f16(af0, CB3, acc[0][3], 0, 0, 0); \
    acc[1][0] = __builtin_amdgcn_mfma_f32_16x16x32_f16(af1, CB0, acc[1][0], 0, 0, 0); \
    acc[1][1] = __builtin_amdgcn_mfma_f32_16x16x32_f16(af1, CB1, acc[1][1], 0, 0, 0); \
    acc[1][2] = __builtin_amdgcn_mfma_f32_16x16x32_f16(af1, CB2, acc[1][2], 0, 0, 0); \
    acc[1][3] = __builtin_amdgcn_mfma_f32_16x16x32_f16(af1, CB3, acc[1][3], 0, 0, 0); \
    acc[2][0] = __builtin_amdgcn_mfma_f32_16x16x32_f16(af2, CB0, acc[2][0], 0, 0, 0); \
    acc[2][1] = __builtin_amdgcn_mfma_f32_16x16x32_f16(af2, CB1, acc[2][1], 0, 0, 0); \
    acc[2][2] = __builtin_amdgcn_mfma_f32_16x16x32_f16(af2, CB2, acc[2][2], 0, 0, 0); \
    acc[2][3] = __builtin_amdgcn_mfma_f32_16x16x32_f16(af2, CB3, acc[2][3], 0, 0, 0); \
    acc[3][0] = __builtin_amdgcn_mfma_f32_16x16x32_f16(af3, CB0, acc[3][0], 0, 0, 0); \
    acc[3][1] = __builtin_amdgcn_mfma_f32_16x16x32_f16(af3, CB1, acc[3][1], 0, 0, 0); \
    acc[3][2] = __builtin_amdgcn_mfma_f32_16x16x32_f16(af3, CB2, acc[3][2], 0, 0, 0); \
    acc[3][3] = __builtin_amdgcn_mfma_f32_16x16x32_f16(af3, CB3, acc[3][3], 0, 0, 0); \
    __builtin_amdgcn_s_setprio(0);                                            \
  }

  KPH16(bU0, bU1, bU2, bU3, bV0, bV1, bV2, bV3, 0)
  KPH16(bV0, bV1, bV2, bV3, bU0, bU1, bU2, bU3, 1)
  KPH16(bU0, bU1, bU2, bU3, bV0, bV1, bV2, bV3, 2)
  KPH16(bV0, bV1, bV2, bV3, bU0, bU1, bU2, bU3, 3)
  KPH16(bU0, bU1, bU2, bU3, bV0, bV1, bV2, bV3, 4)
  KPH16(bV0, bV1, bV2, bV3, bU0, bU1, bU2, bU3, 5)
  KPH16(bU0, bU1, bU2, bU3, bV0, bV1, bV2, bV3, 6)
  KPH16(bV0, bV1, bV2, bV3, bU0, bU1, bU2, bU3, 7)
#undef KPH16

  __syncthreads();   // all waves done reading As -> safe to reuse as mbuf
  float4* mbuf = (float4*)As;

  float e2r[16];
#pragma unroll
  for (int mf = 0; mf < 4; ++mf)
#pragma unroll
    for (int v = 0; v < 4; ++v)
      e2r[mf * 4 + v] = e2[c0 + wm * 64 + mf * 16 + quad * 4 + v];

#pragma unroll
  for (int nf = 0; nf < 4; ++nf) {
    float d1 = 1e30f, d2 = 1e30f; int k1 = 0, k2 = 0;
#pragma unroll
    for (int mf = 0; mf < 4; ++mf)
#pragma unroll
      for (int v = 0; v < 4; ++v) {
        float d = fmaf(-2.0f, acc[mf][nf][v], e2r[mf * 4 + v]);
        int kc = c0 + wm * 64 + mf * 16 + quad * 4 + v;
        bool lt1 = d < d1, lt2 = d < d2;
        d2 = lt1 ? d1 : (lt2 ? d : d2);
        k2 = lt1 ? k1 : (lt2 ? kc : k2);
        d1 = lt1 ? d : d1;
        k1 = lt1 ? kc : k1;
      }
#pragma unroll
    for (int m = 16; m < 64; m <<= 1) {
      float od1 = __shfl_xor(d1, m, 64); int ok1 = __shfl_xor(k1, m, 64);
      float od2 = __shfl_xor(d2, m, 64); int ok2 = __shfl_xor(k2, m, 64);
      merge2(d1, k1, d2, k2, od1, ok1, od2, ok2);
    }
    if (quad == 0)
      mbuf[(wm * 2 + wn) * 64 + nf * 16 + col] =
          make_float4(d1, d2, __int_as_float(k1), __int_as_float(k2));
  }
  __syncthreads();
  if (tid < 128) {
    const int wnn = tid >> 6, zc = tid & 63;
    float4 a = mbuf[(0 * 2 + wnn) * 64 + zc];
    float4 b = mbuf[(1 * 2 + wnn) * 64 + zc];
    float d1 = a.x, d2 = a.y; int k1 = __float_as_int(a.z), k2 = __float_as_int(a.w);
    merge2(d1, k1, d2, k2, b.x, __float_as_int(b.z), b.y, __float_as_int(b.w));
    // [zt][ct][row_local]: tid 0..127 -> one contiguous 2 KB store run
    top2[((size_t)zt * 64 + ct) * 128 + tid] =
        make_float4(d1, d2, __int_as_float(k1), __int_as_float(k2));
  }
}

// ---------- fused refine + gather + STE + per-row loss; 64 sublists/row ----------
__global__ __launch_bounds__(256) void k_refine_gather(
    const float* __restrict__ z, const float* __restrict__ emb_n,
    const float* __restrict__ e2, const float4* __restrict__ top2,
    float* __restrict__ out0, float* __restrict__ idx_out,
    float* __restrict__ lsum, int* __restrict__ wl_row,
    unsigned long long* __restrict__ wl_mask, double* __restrict__ wl_best,
    int* __restrict__ wl_bk, int* __restrict__ n_flag) {
  __shared__ float zr[4][D];
  __shared__ float4 t2s[4][64];
  const int t = threadIdx.x;
  const int w = t >> 6, l = t & 63;
  const int row = blockIdx.x * 4 + w;
  float4 zv = ((const float4*)(z + (size_t)row * D))[l];
  float s = wave_sum(dot4(zv, zv));
  float inv = 1.0f / sqrtf(s + 1e-12f);
  float4 zn = make_float4(zv.x * inv, zv.y * inv, zv.z * inv, zv.w * inv);
  ((float4*)zr[w])[l] = zn;
  // coalesced top2 stage: thread t loads (ct = t>>2, local row = t&3)
  {
    const int zt = (blockIdx.x * 4) >> 7;
    const int rb = (blockIdx.x * 4) & 127;
    t2s[t & 3][t >> 2] = top2[((size_t)zt * 64 + (t >> 2)) * 128 + rb + (t & 3)];
  }
  __syncthreads();

  float4 e = t2s[w][l];
  const float ad1 = e.x, ad2 = e.y;
  const int ck1 = __float_as_int(e.z), ck2 = __float_as_int(e.w);
  const float d1g = wave_min_f(ad1);
  const float win = d1g + 2.0f * MARGIN;

  double best = 1e300; int bk = 0x7fffffff;
  unsigned long long m1 = __ballot(ad1 <= win);
  unsigned long long m2 = __ballot(ad2 <= win);  // sublist rescan mask (64 bits)
#pragma unroll 1
  for (int slot = 0; slot < 2; ++slot) {
    unsigned long long mm = slot ? m2 : m1;
    while (mm) {
      int ln = __builtin_ctzll(mm); mm &= mm - 1;
      int k = __shfl(slot ? ck2 : ck1, ln, 64);
      float4 e4 = ((const float4*)(emb_n + (size_t)k * D))[l];
      float4 z4 = ((const float4*)zr[w])[l];
      double p = (double)e4.x * (double)z4.x + (double)e4.y * (double)z4.y +
                 (double)e4.z * (double)z4.z + (double)e4.w * (double)z4.w;
#pragma unroll
      for (int off = 32; off; off >>= 1) p += __shfl_xor(p, off, 64);
      double dd = (double)e2[k] - 2.0 * p;
      if (dd < best || (dd == best && k < bk)) { best = dd; bk = k; }
    }
  }
  float4 q = ((const float4*)(emb_n + (size_t)bk * D))[l];
  float4 o;
  o.x = zv.x + (q.x - zv.x); o.y = zv.y + (q.y - zv.y);
  o.z = zv.z + (q.z - zv.z); o.w = zv.w + (q.w - zv.w);
  ((float4*)(out0 + (size_t)row * D))[l] = o;
  float dx = q.x - zn.x, dy = q.y - zn.y, dz = q.z - zn.z, dw = q.w - zn.w;
  float lp = wave_sum(dx * dx + dy * dy + dz * dz + dw * dw);
  if (l == 0) {
    lsum[row] = lp;
    idx_out[row] = (float)bk;
    if (m2) {  // some sublist's 3rd+ code could still be in the window
      int p = atomicAdd(n_flag, 1);
      wl_row[p] = row; wl_mask[p] = m2; wl_best[p] = best; wl_bk[p] = bk;
    }
  }
}

// ---------- exact fp64 rescan of flagged sublists (128 codes, 2 thr/code) ----------
__global__ __launch_bounds__(256) void k_rescan(
    const float* __restrict__ z, const float* __restrict__ emb_n,
    const float* __restrict__ e2, const int* __restrict__ wl_row,
    const unsigned long long* __restrict__ wl_mask,
    const double* __restrict__ wl_best, const int* __restrict__ wl_bk,
    const int* __restrict__ n_flag, float* __restrict__ idx_out,
    float* __restrict__ out0, float* __restrict__ lsum) {
  __shared__ float zr[D];
  __shared__ double ph[128];
  __shared__ double sd[4];
  __shared__ int si[4];
  __shared__ int s_bk;
  const int tid = threadIdx.x;
  const int nf = *n_flag;
  for (int wi = blockIdx.x; wi < nf; wi += gridDim.x) {
    const int row = wl_row[wi];
    unsigned long long mask = wl_mask[wi];   // block-uniform
    __syncthreads();  // protect zr/ph across iterations
    if (tid < 64) {
      float4 zv = ((const float4*)(z + (size_t)row * D))[tid];
      float s = wave_sum(dot4(zv, zv));
      float inv = 1.0f / sqrtf(s + 1e-12f);
      ((float4*)zr)[tid] = make_float4(zv.x * inv, zv.y * inv, zv.z * inv, zv.w * inv);
    }
    __syncthreads();
    double best = wl_best[wi]; int bk = wl_bk[wi];
    while (mask) {
      const int sl = __builtin_ctzll(mask); mask &= mask - 1;
      const int code = (sl << 7) + (tid & 127);
      const int half = tid >> 7;
      const float4* ev = (const float4*)(emb_n + (size_t)code * D) + half * 32;
      const float4* zf = ((const float4*)zr) + half * 32;
      double a0 = 0.0, a1 = 0.0;
#pragma unroll 8
      for (int i = 0; i < 32; i += 2) {
        float4 e0 = ev[i], e1 = ev[i + 1], z0 = zf[i], z1 = zf[i + 1];
        a0 += (double)e0.x * (double)z0.x + (double)e0.y * (double)z0.y +
              (double)e0.z * (double)z0.z + (double)e0.w * (double)z0.w;
        a1 += (double)e1.x * (double)z1.x + (double)e1.y * (double)z1.y +
              (double)e1.z * (double)z1.z + (double)e1.w * (double)z1.w;
      }
      double p = a0 + a1;
      if (half) ph[tid & 127] = p;
      __syncthreads();
      if (!half) {
        double dd = (double)e2[code] - 2.0 * (p + ph[tid]);
        if (dd < best || (dd == best && code < bk)) { best = dd; bk = code; }
      }
      __syncthreads();
    }
#pragma unroll
    for (int off = 32; off; off >>= 1) {
      double od = __shfl_xor(best, off, 64); int ok = __shfl_xor(bk, off, 64);
      if (od < best || (od == best && ok < bk)) { best = od; bk = ok; }
    }
    if ((tid & 63) == 0) { sd[tid >> 6] = best; si[tid >> 6] = bk; }
    __syncthreads();
    if (tid == 0) {
#pragma unroll
      for (int q = 1; q < 4; ++q)
        if (sd[q] < best || (sd[q] == best && si[q] < bk)) { best = sd[q]; bk = si[q]; }
      s_bk = bk;
      idx_out[row] = (float)bk;
    }
    __syncthreads();
    const int fk = s_bk;
    if (tid < 64) {
      float4 zv = ((const float4*)(z + (size_t)row * D))[tid];
      float4 zn = ((const float4*)zr)[tid];
      float4 q = ((const float4*)(emb_n + (size_t)fk * D))[tid];
      float4 o;
      o.x = zv.x + (q.x - zv.x); o.y = zv.y + (q.y - zv.y);
      o.z = zv.z + (q.z - zv.z); o.w = zv.w + (q.w - zv.w);
      ((float4*)(out0 + (size_t)row * D))[tid] = o;
      float dx = q.x - zn.x, dy = q.y - zn.y, dz = q.z - zn.z, dw = q.w - zn.w;
      float lp = wave_sum(dx * dx + dy * dy + dz * dz + dw * dw);
      if (tid == 0) lsum[row] = lp;
    }
  }
}

// ---------- final reduce: loss = 1.25 * sum(lsum) / (N*D) ----------
__global__ __launch_bounds__(256) void k_reduce(const float* __restrict__ lsum,
                                                float* __restrict__ loss_out,
                                                float inv_cnt) {
  __shared__ float ws4[4];
  float s = 0.0f;
  const float4* p = (const float4*)lsum;
  for (int i = threadIdx.x; i < NROW / 4; i += 256) {
    float4 v = p[i];
    s += (v.x + v.y) + (v.z + v.w);
  }
  s = wave_sum(s);
  if ((threadIdx.x & 63) == 0) ws4[threadIdx.x >> 6] = s;
  __syncthreads();
  if (threadIdx.x == 0) {
    float m = ((ws4[0] + ws4[1]) + (ws4[2] + ws4[3])) * inv_cnt;
    *loss_out = 0.25f * m + m;
  }
}

// ---------- fallback fp32 path (round-1, proven) ----------
__device__ __forceinline__ int sw_f(int row, int d4) { return row * D + 4 * (d4 ^ (row & 7)); }
__global__ __launch_bounds__(256, 1) void k_argmin_f32(const float* __restrict__ z,
                                                       const float* __restrict__ emb_n,
                                                       const float* __restrict__ e2,
                                                       float* __restrict__ idx_out, int K) {
  extern __shared__ float smem[];
  float* zs = smem; float* es = smem + 64 * D;
  int tid = threadIdx.x; int w = tid >> 6, l = tid & 63;
  size_t r0 = (size_t)blockIdx.x * 64;
#pragma unroll
  for (int i = 0; i < 16; ++i) {
    int row = 4 * i + w;
    float4 v = ((const float4*)(z + (r0 + row) * D))[l];
    float s = wave_sum(dot4(v, v));
    float inv = 1.0f / sqrtf(s + 1e-12f);
    v.x *= inv; v.y *= inv; v.z *= inv; v.w *= inv;
    *(float4*)(&zs[sw_f(row, l)]) = v;
  }
  __syncthreads();
  int tc = tid & 15, tr = tid >> 4;
  float bestd[4] = {1e30f, 1e30f, 1e30f, 1e30f};
  int bestk[4] = {0, 0, 0, 0};
  for (int k0 = 0; k0 < K; k0 += 64) {
#pragma unroll
    for (int i = 0; i < 16; ++i) {
      int row = 4 * i + w;
      float4 v = ((const float4*)(emb_n + (size_t)(k0 + row) * D))[l];
      *(float4*)(&es[sw_f(row, l)]) = v;
    }
    __syncthreads();
    float acc[4][4] = {};
#pragma unroll 4
    for (int d4 = 0; d4 < 64; ++d4) {
      float4 zv[4], ev[4];
#pragma unroll
      for (int i = 0; i < 4; ++i) zv[i] = *(const float4*)(&zs[sw_f(tr + 16 * i, d4)]);
#pragma unroll
      for (int jx = 0; jx < 4; ++jx) ev[jx] = *(const float4*)(&es[sw_f(tc + 16 * jx, d4)]);
#pragma unroll
      for (int i = 0; i < 4; ++i)
#pragma unroll
        for (int jx = 0; jx < 4; ++jx)
          acc[i][jx] = fmaf(zv[i].x, ev[jx].x, fmaf(zv[i].y, ev[jx].y,
                       fmaf(zv[i].z, ev[jx].z, fmaf(zv[i].w, ev[jx].w, acc[i][jx]))));
    }
#pragma unroll
    for (int jx = 0; jx < 4; ++jx) {
      int k = k0 + tc + 16 * jx;
      float ek = e2[k];
#pragma unroll
      for (int i = 0; i < 4; ++i) {
        float dd = fmaf(-2.0f, acc[i][jx], ek);
        if (dd < bestd[i]) { bestd[i] = dd; bestk[i] = k; }
      }
    }
    __syncthreads();
  }
#pragma unroll
  for (int i = 0; i < 4; ++i) {
    float dd = bestd[i]; int kkk = bestk[i];
#pragma unroll
    for (int off = 1; off < 16; off <<= 1) {
      float od = __shfl_xor(dd, off, 64); int ok = __shfl_xor(kkk, off, 64);
      if (od < dd || (od == dd && ok < kkk)) { dd = od; kkk = ok; }
    }
    if (tc == 0) idx_out[r0 + tr + 16 * i] = (float)kkk;
  }
}

__global__ __launch_bounds__(256) void k_gather(const float* __restrict__ z,
                                                const float* __restrict__ emb_n,
                                                const float* __restrict__ idx_f,
                                                float* __restrict__ out0,
                                                float* __restrict__ loss_acc) {
  __shared__ float wsum[4];
  int w = threadIdx.x >> 6, l = threadIdx.x & 63;
  int row = blockIdx.x * 4 + w;
  float4 zv = ((const float4*)(z + (size_t)row * D))[l];
  float s = wave_sum(dot4(zv, zv));
  float inv = 1.0f / sqrtf(s + 1e-12f);
  int k = (int)idx_f[row];
  float4 q = ((const float4*)(emb_n + (size_t)k * D))[l];
  float4 o;
  o.x = zv.x + (q.x - zv.x); o.y = zv.y + (q.y - zv.y);
  o.z = zv.z + (q.z - zv.z); o.w = zv.w + (q.w - zv.w);
  ((float4*)(out0 + (size_t)row * D))[l] = o;
  float dx = q.x - zv.x * inv, dy = q.y - zv.y * inv;
  float dz = q.z - zv.z * inv, dw = q.w - zv.w * inv;
  float lp = wave_sum(dx * dx + dy * dy + dz * dz + dw * dw);
  if (l == 0) wsum[w] = lp;
  __syncthreads();
  if (threadIdx.x == 0) atomicAdd(loss_acc, wsum[0] + wsum[1] + wsum[2] + wsum[3]);
}

__global__ void k_final(const float* __restrict__ loss_acc,
                        float* __restrict__ loss_out, float inv_cnt) {
  float m = *loss_acc * inv_cnt;
  *loss_out = 0.25f * m + m;
}

extern "C" void kernel_launch(void* const* d_in, const int* in_sizes, int n_in,
                              void* d_out, int out_size, void* d_ws, size_t ws_size,
                              hipStream_t stream) {
  const float* z = (const float*)d_in[0];
  const float* emb = (const float*)d_in[1];
  int N = in_sizes[0] / D;  // 16384
  int K = in_sizes[1] / D;  // 8192

  float* out0 = (float*)d_out;
  float* loss_out = out0 + (size_t)N * D;
  float* idx_out = loss_out + 1;

  char* ws = (char*)d_ws;
  float* emb_n = (float*)ws;                            // 8 MB
  float* e2 = (float*)(ws + 8388608);                   // 32 KB
  float* loss_acc = (float*)(ws + 8421376);             // 4 B (fallback)
  int* n_flag = (int*)(ws + 8421380);                   // 4 B
  float* lsum = (float*)(ws + 8421392);                 // 64 KB
  _Float16* Bb = (_Float16*)(ws + 8486928);             // codes fp16 (frag-major), 4 MB
  _Float16* Ab = (_Float16*)(ws + 12681232);            // z fp16 (frag-major), 8 MB
  float4* top2 = (float4*)(ws + 21069840);              // [zt][ct][128], 16 MB
  const size_t NEED = 37847056;
  // Ab dead after gemm -> worklist arrays (row/mask/best/bk)
  int* wl_row = (int*)Ab;
  unsigned long long* wl_mask = (unsigned long long*)((char*)Ab + 65536);
  double* wl_best = (double*)((char*)Ab + 196608);
  int* wl_bk = (int*)((char*)Ab + 327680);

  const float inv_cnt = 1.0f / (float)((size_t)N * D);
  hipMemsetAsync(loss_acc, 0, 8, stream);  // zero loss_acc + n_flag
  if (ws_size >= NEED) {
    k_prep<<<K / 4 + N / 4, 256, 0, stream>>>(emb, z, emb_n, e2, Bb, Ab);
    k_gemm_argmin16<<<(K / 128) * (N / 128), 256, 0, stream>>>(Bb, Ab, e2, top2);
    k_refine_gather<<<N / 4, 256, 0, stream>>>(z, emb_n, e2, top2, out0, idx_out,
                                               lsum, wl_row, wl_mask, wl_best,
                                               wl_bk, n_flag);
    k_rescan<<<1024, 256, 0, stream>>>(z, emb_n, e2, wl_row, wl_mask, wl_best,
                                       wl_bk, n_flag, idx_out, out0, lsum);
    k_reduce<<<1, 256, 0, stream>>>(lsum, loss_out, inv_cnt);
  } else {
    k_prep<<<K / 4 + N / 4, 256, 0, stream>>>(emb, z, emb_n, e2, Bb, Ab);
    k_argmin_f32<<<N / 64, 256, 131072, stream>>>(z, emb_n, e2, idx_out, K);
    k_gather<<<N / 4, 256, 0, stream>>>(z, emb_n, idx_out, out0, loss_acc);
    k_final<<<1, 1, 0, stream>>>(loss_acc, loss_out, inv_cnt);
  }
}

// Round 12
// 195.895 us; speedup vs baseline: 1.0733x; 1.0733x over previous
//
#include <hip/hip_runtime.h>
#include <math.h>

#define D 256
#define NROW 16384
#define KCODE 8192
#define MARGIN 1.2e-3f   // pure-fp16 product: 2*2^-11 = 9.77e-4 worst + accum slack

typedef _Float16 half8 __attribute__((ext_vector_type(8)));
typedef _Float16 half4f __attribute__((ext_vector_type(4)));
typedef __attribute__((ext_vector_type(4))) float f32x4;

__device__ __forceinline__ float dot4(float4 a, float4 b) {
  return a.x * b.x + a.y * b.y + a.z * b.z + a.w * b.w;
}
__device__ __forceinline__ float wave_sum(float s) {
#pragma unroll
  for (int off = 32; off; off >>= 1) s += __shfl_xor(s, off, 64);
  return s;
}
__device__ __forceinline__ float wave_min_f(float v) {
#pragma unroll
  for (int off = 32; off; off >>= 1) v = fminf(v, __shfl_xor(v, off, 64));
  return v;
}

// ---------- combined prep: blocks [0,2048) emb; [2048,6144) z ----------
// fp16 copies are written PRE-SWIZZLED in MFMA-fragment order so the GEMM can
// stream fragments from L2 with perfectly coalesced 1 KB wave loads (no LDS).
// Layout per 128-row tile t (code-tile or z-tile), f16 units:
//   t*32768 + ph*4096 + grp*2048 + f*512 + (quad*16 + col)*8 + k&7
// where row = grp*64 + f*16 + col (grp=row>>6, f=(row>>4)&3, col=row&15),
//       k-chunk: ph = k>>5 (0..7), quad = (k>>3)&3.
// A wave's fragment (grp,f,ph) = rows [base+f*16, +16) x k [ph*32, +32):
// lane l=quad*16+col -> contiguous l*8 f16 -> ONE coalesced 1 KB run.
__global__ __launch_bounds__(256) void k_prep(const float* __restrict__ emb,
                                              const float* __restrict__ z,
                                              float* __restrict__ emb_n,
                                              float* __restrict__ e2,
                                              _Float16* __restrict__ Bb,
                                              _Float16* __restrict__ Ab) {
  const int b = blockIdx.x;
  const int w = threadIdx.x >> 6, l = threadIdx.x & 63;
  // lane l covers k = 4l..4l+3
  const int ph = l >> 3;             // k>>5
  const int qd = (l & 7) >> 1;       // (k>>3)&3
  const int hf = l & 1;              // (k&7)>>2
  if (b < 2048) {
    int row = b * 4 + w;
    float4 v = ((const float4*)(emb + (size_t)row * D))[l];
    float s = wave_sum(dot4(v, v));
    float inv = 1.0f / sqrtf(s + 1e-12f);
    v.x *= inv; v.y *= inv; v.z *= inv; v.w *= inv;
    ((float4*)(emb_n + (size_t)row * D))[l] = v;
    float s2 = wave_sum(dot4(v, v));
    if (l == 0) e2[row] = s2;
    half4f h;
    h[0] = (_Float16)v.x; h[1] = (_Float16)v.y;
    h[2] = (_Float16)v.z; h[3] = (_Float16)v.w;
    int t = row >> 7, r = row & 127;
    size_t off = (size_t)t * 32768 + ph * 4096 + (r >> 6) * 2048 +
                 ((r >> 4) & 3) * 512 + (qd * 16 + (r & 15)) * 8 + hf * 4;
    *(half4f*)(Bb + off) = h;
  } else {
    int row = (b - 2048) * 4 + w;
    float4 v = ((const float4*)(z + (size_t)row * D))[l];
    float s = wave_sum(dot4(v, v));
    float inv = 1.0f / sqrtf(s + 1e-12f);
    v.x *= inv; v.y *= inv; v.z *= inv; v.w *= inv;
    half4f h;
    h[0] = (_Float16)v.x; h[1] = (_Float16)v.y;
    h[2] = (_Float16)v.z; h[3] = (_Float16)v.w;
    int t = row >> 7, r = row & 127;
    size_t off = (size_t)t * 32768 + ph * 4096 + (r >> 6) * 2048 +
                 ((r >> 4) & 3) * 512 + (qd * 16 + (r & 15)) * 8 + hf * 4;
    *(half4f*)(Ab + off) = h;
  }
}

__device__ __forceinline__ void merge2(float& d1, int& k1, float& d2, int& k2,
                                       float od1, int ok1, float od2, int ok2) {
  bool w1 = (od1 < d1) || (od1 == d1 && ok1 < k1);
  float n1 = w1 ? od1 : d1; int nk1 = w1 ? ok1 : k1;
  float c  = w1 ? d1 : od1; int ck  = w1 ? k1 : ok1;
  float c2 = w1 ? od2 : d2; int ck2 = w1 ? ok2 : k2;
  bool w2 = (c2 < c) || (c2 == c && ck2 < ck);
  d1 = n1; k1 = nk1;
  d2 = w2 ? c2 : c; k2 = w2 ? ck2 : ck;
}

// ---------- 128x128 fp16 GEMM (codes x z), K'=256, fused top-2 ----------
// v10 (SESSION BEST, 92.4 us GEMM / 198.8 us total): ZERO-LDS, ZERO-BARRIER
// main loop. Both operands stream from L2 as pre-swizzled fragment-major 1 KB
// coalesced wave loads (see k_prep). 8 k-phases (k-chunk = 32), ping-pong
// register prefetch depth 1 (all indices static). Same accumulation order as
// v6 -> bit-identical results. Reinstated after v11-v16 (32x32 rate, deeper
// pipeline, occupancy trade, LDS hybrid) all measured behind it.
__global__ __launch_bounds__(256, 3) void k_gemm_argmin10(
    const _Float16* __restrict__ Cb,   // codes fp16, fragment-major
    const _Float16* __restrict__ Zb,   // z fp16, fragment-major
    const float* __restrict__ e2, float4* __restrict__ top2) {
  __shared__ float4 mbuf[256];
  const int tid = threadIdx.x, w = tid >> 6, l = tid & 63;
  const int wm = w >> 1, wn = w & 1;
  const int quad = l >> 4, col = l & 15;
  const int xcd = blockIdx.x & 7;
  const int j = blockIdx.x >> 3;
  const int ct = xcd * 8 + (j & 7);          // code tile 0..63
  const int zt = j >> 3;                     // z tile 0..127
  const int c0 = ct * 128;

  const _Float16* At = Cb + (size_t)ct * 32768 + wm * 2048 + (size_t)l * 8;
  const _Float16* Bt = Zb + (size_t)zt * 32768 + wn * 2048 + (size_t)l * 8;

  f32x4 acc[4][4] = {};
  half8 a0[4], b0[4], a1[4], b1[4];
#pragma unroll
  for (int mf = 0; mf < 4; ++mf) {
    a0[mf] = *(const half8*)(At + mf * 512);
    b0[mf] = *(const half8*)(Bt + mf * 512);
  }
#pragma unroll
  for (int ph = 0; ph < 8; ph += 2) {
    // prefetch phase ph+1 while computing ph
#pragma unroll
    for (int mf = 0; mf < 4; ++mf) {
      a1[mf] = *(const half8*)(At + (ph + 1) * 4096 + mf * 512);
      b1[mf] = *(const half8*)(Bt + (ph + 1) * 4096 + mf * 512);
    }
    __builtin_amdgcn_s_setprio(1);
#pragma unroll
    for (int mf = 0; mf < 4; ++mf)
#pragma unroll
      for (int nf = 0; nf < 4; ++nf)
        acc[mf][nf] = __builtin_amdgcn_mfma_f32_16x16x32_f16(a0[mf], b0[nf], acc[mf][nf], 0, 0, 0);
    __builtin_amdgcn_s_setprio(0);
    if (ph < 6) {
      // prefetch phase ph+2 while computing ph+1
#pragma unroll
      for (int mf = 0; mf < 4; ++mf) {
        a0[mf] = *(const half8*)(At + (ph + 2) * 4096 + mf * 512);
        b0[mf] = *(const half8*)(Bt + (ph + 2) * 4096 + mf * 512);
      }
    }
    __builtin_amdgcn_s_setprio(1);
#pragma unroll
    for (int mf = 0; mf < 4; ++mf)
#pragma unroll
      for (int nf = 0; nf < 4; ++nf)
        acc[mf][nf] = __builtin_amdgcn_mfma_f32_16x16x32_f16(a1[mf], b1[nf], acc[mf][nf], 0, 0, 0);
    __builtin_amdgcn_s_setprio(0);
  }

  float e2r[16];
#pragma unroll
  for (int mf = 0; mf < 4; ++mf)
#pragma unroll
    for (int v = 0; v < 4; ++v)
      e2r[mf * 4 + v] = e2[c0 + wm * 64 + mf * 16 + quad * 4 + v];

#pragma unroll
  for (int nf = 0; nf < 4; ++nf) {
    float d1 = 1e30f, d2 = 1e30f; int k1 = 0, k2 = 0;
#pragma unroll
    for (int mf = 0; mf < 4; ++mf)
#pragma unroll
      for (int v = 0; v < 4; ++v) {
        float d = fmaf(-2.0f, acc[mf][nf][v], e2r[mf * 4 + v]);
        int kc = c0 + wm * 64 + mf * 16 + quad * 4 + v;
        bool lt1 = d < d1, lt2 = d < d2;
        d2 = lt1 ? d1 : (lt2 ? d : d2);
        k2 = lt1 ? k1 : (lt2 ? kc : k2);
        d1 = lt1 ? d : d1;
        k1 = lt1 ? kc : k1;
      }
#pragma unroll
    for (int m = 16; m < 64; m <<= 1) {
      float od1 = __shfl_xor(d1, m, 64); int ok1 = __shfl_xor(k1, m, 64);
      float od2 = __shfl_xor(d2, m, 64); int ok2 = __shfl_xor(k2, m, 64);
      merge2(d1, k1, d2, k2, od1, ok1, od2, ok2);
    }
    if (quad == 0)
      mbuf[(wm * 2 + wn) * 64 + nf * 16 + col] =
          make_float4(d1, d2, __int_as_float(k1), __int_as_float(k2));
  }
  __syncthreads();
  if (tid < 128) {
    const int wnn = tid >> 6, zc = tid & 63;
    float4 a = mbuf[(0 * 2 + wnn) * 64 + zc];
    float4 b = mbuf[(1 * 2 + wnn) * 64 + zc];
    float d1 = a.x, d2 = a.y; int k1 = __float_as_int(a.z), k2 = __float_as_int(a.w);
    merge2(d1, k1, d2, k2, b.x, __float_as_int(b.z), b.y, __float_as_int(b.w));
    // [zt][ct][row_local]: tid 0..127 -> one contiguous 2 KB store run
    top2[((size_t)zt * 64 + ct) * 128 + tid] =
        make_float4(d1, d2, __int_as_float(k1), __int_as_float(k2));
  }
}

// ---------- fused refine + gather + STE + per-row loss; 64 sublists/row ----------
__global__ __launch_bounds__(256) void k_refine_gather(
    const float* __restrict__ z, const float* __restrict__ emb_n,
    const float* __restrict__ e2, const float4* __restrict__ top2,
    float* __restrict__ out0, float* __restrict__ idx_out,
    float* __restrict__ lsum, int* __restrict__ wl_row,
    unsigned long long* __restrict__ wl_mask, double* __restrict__ wl_best,
    int* __restrict__ wl_bk, int* __restrict__ n_flag) {
  __shared__ float zr[4][D];
  __shared__ float4 t2s[4][64];
  const int t = threadIdx.x;
  const int w = t >> 6, l = t & 63;
  const int row = blockIdx.x * 4 + w;
  float4 zv = ((const float4*)(z + (size_t)row * D))[l];
  float s = wave_sum(dot4(zv, zv));
  float inv = 1.0f / sqrtf(s + 1e-12f);
  float4 zn = make_float4(zv.x * inv, zv.y * inv, zv.z * inv, zv.w * inv);
  ((float4*)zr[w])[l] = zn;
  // coalesced top2 stage: thread t loads (ct = t>>2, local row = t&3)
  {
    const int zt = (blockIdx.x * 4) >> 7;
    const int rb = (blockIdx.x * 4) & 127;
    t2s[t & 3][t >> 2] = top2[((size_t)zt * 64 + (t >> 2)) * 128 + rb + (t & 3)];
  }
  __syncthreads();

  float4 e = t2s[w][l];
  const float ad1 = e.x, ad2 = e.y;
  const int ck1 = __float_as_int(e.z), ck2 = __float_as_int(e.w);
  const float d1g = wave_min_f(ad1);
  const float win = d1g + 2.0f * MARGIN;

  double best = 1e300; int bk = 0x7fffffff;
  unsigned long long m1 = __ballot(ad1 <= win);
  unsigned long long m2 = __ballot(ad2 <= win);  // sublist rescan mask (64 bits)
#pragma unroll 1
  for (int slot = 0; slot < 2; ++slot) {
    unsigned long long mm = slot ? m2 : m1;
    while (mm) {
      int ln = __builtin_ctzll(mm); mm &= mm - 1;
      int k = __shfl(slot ? ck2 : ck1, ln, 64);
      float4 e4 = ((const float4*)(emb_n + (size_t)k * D))[l];
      float4 z4 = ((const float4*)zr[w])[l];
      double p = (double)e4.x * (double)z4.x + (double)e4.y * (double)z4.y +
                 (double)e4.z * (double)z4.z + (double)e4.w * (double)z4.w;
#pragma unroll
      for (int off = 32; off; off >>= 1) p += __shfl_xor(p, off, 64);
      double dd = (double)e2[k] - 2.0 * p;
      if (dd < best || (dd == best && k < bk)) { best = dd; bk = k; }
    }
  }
  float4 q = ((const float4*)(emb_n + (size_t)bk * D))[l];
  float4 o;
  o.x = zv.x + (q.x - zv.x); o.y = zv.y + (q.y - zv.y);
  o.z = zv.z + (q.z - zv.z); o.w = zv.w + (q.w - zv.w);
  ((float4*)(out0 + (size_t)row * D))[l] = o;
  float dx = q.x - zn.x, dy = q.y - zn.y, dz = q.z - zn.z, dw = q.w - zn.w;
  float lp = wave_sum(dx * dx + dy * dy + dz * dz + dw * dw);
  if (l == 0) {
    lsum[row] = lp;
    idx_out[row] = (float)bk;
    if (m2) {  // some sublist's 3rd+ code could still be in the window
      int p = atomicAdd(n_flag, 1);
      wl_row[p] = row; wl_mask[p] = m2; wl_best[p] = best; wl_bk[p] = bk;
    }
  }
}

// ---------- exact fp64 rescan of flagged sublists (128 codes, 2 thr/code) ----------
__global__ __launch_bounds__(256) void k_rescan(
    const float* __restrict__ z, const float* __restrict__ emb_n,
    const float* __restrict__ e2, const int* __restrict__ wl_row,
    const unsigned long long* __restrict__ wl_mask,
    const double* __restrict__ wl_best, const int* __restrict__ wl_bk,
    const int* __restrict__ n_flag, float* __restrict__ idx_out,
    float* __restrict__ out0, float* __restrict__ lsum) {
  __shared__ float zr[D];
  __shared__ double ph[128];
  __shared__ double sd[4];
  __shared__ int si[4];
  __shared__ int s_bk;
  const int tid = threadIdx.x;
  const int nf = *n_flag;
  for (int wi = blockIdx.x; wi < nf; wi += gridDim.x) {
    const int row = wl_row[wi];
    unsigned long long mask = wl_mask[wi];   // block-uniform
    __syncthreads();  // protect zr/ph across iterations
    if (tid < 64) {
      float4 zv = ((const float4*)(z + (size_t)row * D))[tid];
      float s = wave_sum(dot4(zv, zv));
      float inv = 1.0f / sqrtf(s + 1e-12f);
      ((float4*)zr)[tid] = make_float4(zv.x * inv, zv.y * inv, zv.z * inv, zv.w * inv);
    }
    __syncthreads();
    double best = wl_best[wi]; int bk = wl_bk[wi];
    while (mask) {
      const int sl = __builtin_ctzll(mask); mask &= mask - 1;
      const int code = (sl << 7) + (tid & 127);
      const int half = tid >> 7;
      const float4* ev = (const float4*)(emb_n + (size_t)code * D) + half * 32;
      const float4* zf = ((const float4*)zr) + half * 32;
      double a0 = 0.0, a1 = 0.0;
#pragma unroll 8
      for (int i = 0; i < 32; i += 2) {
        float4 e0 = ev[i], e1 = ev[i + 1], z0 = zf[i], z1 = zf[i + 1];
        a0 += (double)e0.x * (double)z0.x + (double)e0.y * (double)z0.y +
              (double)e0.z * (double)z0.z + (double)e0.w * (double)z0.w;
        a1 += (double)e1.x * (double)z1.x + (double)e1.y * (double)z1.y +
              (double)e1.z * (double)z1.z + (double)e1.w * (double)z1.w;
      }
      double p = a0 + a1;
      if (half) ph[tid & 127] = p;
      __syncthreads();
      if (!half) {
        double dd = (double)e2[code] - 2.0 * (p + ph[tid]);
        if (dd < best || (dd == best && code < bk)) { best = dd; bk = code; }
      }
      __syncthreads();
    }
#pragma unroll
    for (int off = 32; off; off >>= 1) {
      double od = __shfl_xor(best, off, 64); int ok = __shfl_xor(bk, off, 64);
      if (od < best || (od == best && ok < bk)) { best = od; bk = ok; }
    }
    if ((tid & 63) == 0) { sd[tid >> 6] = best; si[tid >> 6] = bk; }
    __syncthreads();
    if (tid == 0) {
#pragma unroll
      for (int q = 1; q < 4; ++q)
        if (sd[q] < best || (sd[q] == best && si[q] < bk)) { best = sd[q]; bk = si[q]; }
      s_bk = bk;
      idx_out[row] = (float)bk;
    }
    __syncthreads();
    const int fk = s_bk;
    if (tid < 64) {
      float4 zv = ((const float4*)(z + (size_t)row * D))[tid];
      float4 zn = ((const float4*)zr)[tid];
      float4 q = ((const float4*)(emb_n + (size_t)fk * D))[tid];
      float4 o;
      o.x = zv.x + (q.x - zv.x); o.y = zv.y + (q.y - zv.y);
      o.z = zv.z + (q.z - zv.z); o.w = zv.w + (q.w - zv.w);
      ((float4*)(out0 + (size_t)row * D))[tid] = o;
      float dx = q.x - zn.x, dy = q.y - zn.y, dz = q.z - zn.z, dw = q.w - zn.w;
      float lp = wave_sum(dx * dx + dy * dy + dz * dz + dw * dw);
      if (tid == 0) lsum[row] = lp;
    }
  }
}

// ---------- final reduce: loss = 1.25 * sum(lsum) / (N*D) ----------
__global__ __launch_bounds__(256) void k_reduce(const float* __restrict__ lsum,
                                                float* __restrict__ loss_out,
                                                float inv_cnt) {
  __shared__ float ws4[4];
  float s = 0.0f;
  const float4* p = (const float4*)lsum;
  for (int i = threadIdx.x; i < NROW / 4; i += 256) {
    float4 v = p[i];
    s += (v.x + v.y) + (v.z + v.w);
  }
  s = wave_sum(s);
  if ((threadIdx.x & 63) == 0) ws4[threadIdx.x >> 6] = s;
  __syncthreads();
  if (threadIdx.x == 0) {
    float m = ((ws4[0] + ws4[1]) + (ws4[2] + ws4[3])) * inv_cnt;
    *loss_out = 0.25f * m + m;
  }
}

// ---------- fallback fp32 path (round-1, proven) ----------
__device__ __forceinline__ int sw_f(int row, int d4) { return row * D + 4 * (d4 ^ (row & 7)); }
__global__ __launch_bounds__(256, 1) void k_argmin_f32(const float* __restrict__ z,
                                                       const float* __restrict__ emb_n,
                                                       const float* __restrict__ e2,
                                                       float* __restrict__ idx_out, int K) {
  extern __shared__ float smem[];
  float* zs = smem; float* es = smem + 64 * D;
  int tid = threadIdx.x; int w = tid >> 6, l = tid & 63;
  size_t r0 = (size_t)blockIdx.x * 64;
#pragma unroll
  for (int i = 0; i < 16; ++i) {
    int row = 4 * i + w;
    float4 v = ((const float4*)(z + (r0 + row) * D))[l];
    float s = wave_sum(dot4(v, v));
    float inv = 1.0f / sqrtf(s + 1e-12f);
    v.x *= inv; v.y *= inv; v.z *= inv; v.w *= inv;
    *(float4*)(&zs[sw_f(row, l)]) = v;
  }
  __syncthreads();
  int tc = tid & 15, tr = tid >> 4;
  float bestd[4] = {1e30f, 1e30f, 1e30f, 1e30f};
  int bestk[4] = {0, 0, 0, 0};
  for (int k0 = 0; k0 < K; k0 += 64) {
#pragma unroll
    for (int i = 0; i < 16; ++i) {
      int row = 4 * i + w;
      float4 v = ((const float4*)(emb_n + (size_t)(k0 + row) * D))[l];
      *(float4*)(&es[sw_f(row, l)]) = v;
    }
    __syncthreads();
    float acc[4][4] = {};
#pragma unroll 4
    for (int d4 = 0; d4 < 64; ++d4) {
      float4 zv[4], ev[4];
#pragma unroll
      for (int i = 0; i < 4; ++i) zv[i] = *(const float4*)(&zs[sw_f(tr + 16 * i, d4)]);
#pragma unroll
      for (int jx = 0; jx < 4; ++jx) ev[jx] = *(const float4*)(&es[sw_f(tc + 16 * jx, d4)]);
#pragma unroll
      for (int i = 0; i < 4; ++i)
#pragma unroll
        for (int jx = 0; jx < 4; ++jx)
          acc[i][jx] = fmaf(zv[i].x, ev[jx].x, fmaf(zv[i].y, ev[jx].y,
                       fmaf(zv[i].z, ev[jx].z, fmaf(zv[i].w, ev[jx].w, acc[i][jx]))));
    }
#pragma unroll
    for (int jx = 0; jx < 4; ++jx) {
      int k = k0 + tc + 16 * jx;
      float ek = e2[k];
#pragma unroll
      for (int i = 0; i < 4; ++i) {
        float dd = fmaf(-2.0f, acc[i][jx], ek);
        if (dd < bestd[i]) { bestd[i] = dd; bestk[i] = k; }
      }
    }
    __syncthreads();
  }
#pragma unroll
  for (int i = 0; i < 4; ++i) {
    float dd = bestd[i]; int kkk = bestk[i];
#pragma unroll
    for (int off = 1; off < 16; off <<= 1) {
      float od = __shfl_xor(dd, off, 64); int ok = __shfl_xor(kkk, off, 64);
      if (od < dd || (od == dd && ok < kkk)) { dd = od; kkk = ok; }
    }
    if (tc == 0) idx_out[r0 + tr + 16 * i] = (float)kkk;
  }
}

__global__ __launch_bounds__(256) void k_gather(const float* __restrict__ z,
                                                const float* __restrict__ emb_n,
                                                const float* __restrict__ idx_f,
                                                float* __restrict__ out0,
                                                float* __restrict__ loss_acc) {
  __shared__ float wsum[4];
  int w = threadIdx.x >> 6, l = threadIdx.x & 63;
  int row = blockIdx.x * 4 + w;
  float4 zv = ((const float4*)(z + (size_t)row * D))[l];
  float s = wave_sum(dot4(zv, zv));
  float inv = 1.0f / sqrtf(s + 1e-12f);
  int k = (int)idx_f[row];
  float4 q = ((const float4*)(emb_n + (size_t)k * D))[l];
  float4 o;
  o.x = zv.x + (q.x - zv.x); o.y = zv.y + (q.y - zv.y);
  o.z = zv.z + (q.z - zv.z); o.w = zv.w + (q.w - zv.w);
  ((float4*)(out0 + (size_t)row * D))[l] = o;
  float dx = q.x - zv.x * inv, dy = q.y - zv.y * inv;
  float dz = q.z - zv.z * inv, dw = q.w - zv.w * inv;
  float lp = wave_sum(dx * dx + dy * dy + dz * dz + dw * dw);
  if (l == 0) wsum[w] = lp;
  __syncthreads();
  if (threadIdx.x == 0) atomicAdd(loss_acc, wsum[0] + wsum[1] + wsum[2] + wsum[3]);
}

__global__ void k_final(const float* __restrict__ loss_acc,
                        float* __restrict__ loss_out, float inv_cnt) {
  float m = *loss_acc * inv_cnt;
  *loss_out = 0.25f * m + m;
}

extern "C" void kernel_launch(void* const* d_in, const int* in_sizes, int n_in,
                              void* d_out, int out_size, void* d_ws, size_t ws_size,
                              hipStream_t stream) {
  const float* z = (const float*)d_in[0];
  const float* emb = (const float*)d_in[1];
  int N = in_sizes[0] / D;  // 16384
  int K = in_sizes[1] / D;  // 8192

  float* out0 = (float*)d_out;
  float* loss_out = out0 + (size_t)N * D;
  float* idx_out = loss_out + 1;

  char* ws = (char*)d_ws;
  float* emb_n = (float*)ws;                            // 8 MB
  float* e2 = (float*)(ws + 8388608);                   // 32 KB
  float* loss_acc = (float*)(ws + 8421376);             // 4 B (fallback)
  int* n_flag = (int*)(ws + 8421380);                   // 4 B
  float* lsum = (float*)(ws + 8421392);                 // 64 KB
  _Float16* Bb = (_Float16*)(ws + 8486928);             // codes fp16 (frag-major), 4 MB
  _Float16* Ab = (_Float16*)(ws + 12681232);            // z fp16 (frag-major), 8 MB
  float4* top2 = (float4*)(ws + 21069840);              // [zt][ct][128], 16 MB
  const size_t NEED = 37847056;
  // Ab dead after gemm -> worklist arrays (row/mask/best/bk)
  int* wl_row = (int*)Ab;
  unsigned long long* wl_mask = (unsigned long long*)((char*)Ab + 65536);
  double* wl_best = (double*)((char*)Ab + 196608);
  int* wl_bk = (int*)((char*)Ab + 327680);

  const float inv_cnt = 1.0f / (float)((size_t)N * D);
  hipMemsetAsync(loss_acc, 0, 8, stream);  // zero loss_acc + n_flag
  if (ws_size >= NEED) {
    k_prep<<<K / 4 + N / 4, 256, 0, stream>>>(emb, z, emb_n, e2, Bb, Ab);
    k_gemm_argmin10<<<(K / 128) * (N / 128), 256, 0, stream>>>(Bb, Ab, e2, top2);
    k_refine_gather<<<N / 4, 256, 0, stream>>>(z, emb_n, e2, top2, out0, idx_out,
                                               lsum, wl_row, wl_mask, wl_best,
                                               wl_bk, n_flag);
    k_rescan<<<1024, 256, 0, stream>>>(z, emb_n, e2, wl_row, wl_mask, wl_best,
                                       wl_bk, n_flag, idx_out, out0, lsum);
    k_reduce<<<1, 256, 0, stream>>>(lsum, loss_out, inv_cnt);
  } else {
    k_prep<<<K / 4 + N / 4, 256, 0, stream>>>(emb, z, emb_n, e2, Bb, Ab);
    k_argmin_f32<<<N / 64, 256, 131072, stream>>>(z, emb_n, e2, idx_out, K);
    k_gather<<<N / 4, 256, 0, stream>>>(z, emb_n, idx_out, out0, loss_acc);
    k_final<<<1, 1, 0, stream>>>(loss_acc, loss_out, inv_cnt);
  }
}